// Round 10
// baseline (247.695 us; speedup 1.0000x reference)
//
#include <hip/hip_runtime.h>

// Exact-arithmetic replication of the JAX reference: no FMA contraction.
#pragma clang fp contract(off)

#define KK 12
#define EPS_Z 0.001f
#define BIG 1.0e10f

// JAX linspace(0,1,12): delta = f32(1/11) (one rounded division), t_k = k*delta.
#define T_DELTA (1.0f / 11.0f)

// "Empty" sentinel: max uint in mapped order; any real depth beats it.
#define Z_EMPTY 0xFFFFFFFFu

// Order-preserving float -> uint mapping (monotone for all finite floats,
// including negatives), so atomicMin(uint) == float min.
__device__ __forceinline__ unsigned int fmap(float f) {
    unsigned int u = __float_as_uint(f);
    return (u & 0x80000000u) ? ~u : (u | 0x80000000u);
}
__device__ __forceinline__ float funmap(unsigned int u) {
    return (u & 0x80000000u) ? __uint_as_float(u ^ 0x80000000u)
                             : __uint_as_float(~u);
}

__global__ void init_zbuf(unsigned int* __restrict__ zbuf,
                          const int* __restrict__ pH, const int* __restrict__ pW) {
    int total = pH[0] * pW[0];
    for (int i = blockIdx.x * blockDim.x + threadIdx.x; i < total;
         i += gridDim.x * blockDim.x)
        zbuf[i] = Z_EMPTY;
}

// One thread per (triangle, i) where i indexes the px sample (blockIdx.y).
// Each thread walks the 12 py samples. Losing atomics are filtered by a
// cached (possibly stale, always conservative) read of the current zbuf:
// zbuf values only decrease, so stale==larger -> we still atomic (correct);
// if hint <= our depth, the atomic would be a no-op -> skip (correct).
__global__ void raster(const float* __restrict__ verts, const int* __restrict__ tris,
                       int T, const int* __restrict__ pH, const int* __restrict__ pW,
                       unsigned int* zbuf) {
#pragma clang fp contract(off)
    int t = blockIdx.x * blockDim.x + threadIdx.x;
    if (t >= T) return;
    const int i = blockIdx.y;
    const int W = pW[0];
    const int H = pH[0];
    const float Wm1 = (float)(W - 1);
    const float Hm1 = (float)(H - 1);

    int i0 = tris[t * 3 + 0], i1 = tris[t * 3 + 1], i2 = tris[t * 3 + 2];
    float x0 = verts[i0 * 3 + 0], y0 = verts[i0 * 3 + 1], z0 = verts[i0 * 3 + 2];
    float x1 = verts[i1 * 3 + 0], y1 = verts[i1 * 3 + 1], z1 = verts[i1 * 3 + 2];
    float x2 = verts[i2 * 3 + 0], y2 = verts[i2 * 3 + 1], z2 = verts[i2 * 3 + 2];

    // area exactly as reference
    float area = (x2 - x0) * (y1 - y0) - (y2 - y0) * (x1 - x0);
    if (!(fabsf(area) > 1e-8f)) return;  // all samples invalid -> BIG -> no-op

    float xmin = fminf(x0, fminf(x1, x2));
    float xmax = fmaxf(x0, fmaxf(x1, x2));
    float ymin = fminf(y0, fminf(y1, y2));
    float ymax = fmaxf(y0, fmaxf(y1, y2));

    // t_i = f32(i) * f32(1/11)  — matches jnp.linspace exactly (NOT i/11).
    float ti = (float)i * T_DELTA;
    float px = xmin + ti * (xmax - xmin);
    if (!(px >= 0.0f && px <= Wm1)) return;  // in_img fails for this whole column

    int ix = (int)fminf(fmaxf(rintf(px), 0.0f), Wm1);

    // Edge constants (hoisting products keeps identical f32 values).
    float e0dy = y2 - y1, e0dx = x2 - x1;  // edge(v1,v2)
    float e1dy = y0 - y2, e1dx = x0 - x2;  // edge(v2,v0)
    float e2dy = y1 - y0, e2dx = x1 - x0;  // edge(v0,v1)
    float a0 = (px - x1) * e0dy;
    float a1 = (px - x2) * e1dy;
    float a2 = (px - x0) * e2dy;

    float dy = ymax - ymin;
#pragma unroll
    for (int j = 0; j < KK; ++j) {
        float tj = (float)j * T_DELTA;  // compile-time, matches linspace
        float py = ymin + tj * dy;
        if (!(py >= 0.0f && py <= Hm1)) continue;
        float w0 = a0 - (py - y1) * e0dx;
        float w1 = a1 - (py - y2) * e1dx;
        float w2 = a2 - (py - y0) * e2dx;
        bool inside = (w0 >= 0.0f && w1 >= 0.0f && w2 >= 0.0f) ||
                      (w0 <= 0.0f && w1 <= 0.0f && w2 <= 0.0f);
        if (!inside) continue;
        float depth = ((w0 * z0 + w1 * z1) + w2 * z2) / area;  // left-assoc as XLA
        int iy = (int)fminf(fmaxf(rintf(py), 0.0f), Hm1);
        int idx = iy * W + ix;
        unsigned int d = fmap(depth);
        unsigned int hint = zbuf[idx];   // cached read; stale is conservative
        if (d < hint) atomicMin(&zbuf[idx], d);
    }
}

__global__ void visible_k(const float* __restrict__ verts, int N,
                          const int* __restrict__ pH, const int* __restrict__ pW,
                          const unsigned int* __restrict__ zbuf,
                          float* __restrict__ out) {
#pragma clang fp contract(off)
    int n = blockIdx.x * blockDim.x + threadIdx.x;
    if (n >= N) return;
    const int W = pW[0];
    const int H = pH[0];
    const float Wm1 = (float)(W - 1);
    const float Hm1 = (float)(H - 1);
    float x = verts[n * 3 + 0], y = verts[n * 3 + 1], z = verts[n * 3 + 2];
    bool in_img = (x >= 0.0f) && (x <= Wm1) && (y >= 0.0f) && (y <= Hm1);
    float r = 0.0f;
    if (in_img) {
        int ix = (int)fminf(fmaxf(rintf(x), 0.0f), Wm1);
        int iy = (int)fminf(fmaxf(rintf(y), 0.0f), Hm1);
        unsigned int u = zbuf[iy * W + ix];
        float zb = (u == Z_EMPTY) ? BIG : funmap(u);
        r = (z <= zb + EPS_Z) ? 1.0f : 0.0f;
    }
    out[n] = r;
}

extern "C" void kernel_launch(void* const* d_in, const int* in_sizes, int n_in,
                              void* d_out, int out_size, void* d_ws, size_t ws_size,
                              hipStream_t stream) {
    const float* verts = (const float*)d_in[0];
    const int* tris = (const int*)d_in[1];
    const int* pH = (const int*)d_in[2];
    const int* pW = (const int*)d_in[3];
    int N = in_sizes[0] / 3;
    int T = in_sizes[1] / 3;
    unsigned int* zbuf = (unsigned int*)d_ws;  // H*W uints (1 MB at 512x512)

    init_zbuf<<<1024, 256, 0, stream>>>(zbuf, pH, pW);
    dim3 rgrid((T + 255) / 256, KK);
    raster<<<rgrid, 256, 0, stream>>>(verts, tris, T, pH, pW, zbuf);
    visible_k<<<(N + 255) / 256, 256, 0, stream>>>(verts, N, pH, pW, zbuf,
                                                   (float*)d_out);
}

// Round 12
// 234.987 us; speedup vs baseline: 1.0541x; 1.0541x over previous
//
#include <hip/hip_runtime.h>

// Exact-arithmetic replication of the JAX reference: no FMA contraction.
#pragma clang fp contract(off)

#define KK 12
#define EPS_Z 0.001f
#define BIG 1.0e10f
#define NXCD 8

// JAX linspace(0,1,12): delta = f32(1/11) (one rounded division), t_k = k*delta.
#define T_DELTA (1.0f / 11.0f)

// "Empty" sentinel: max uint in mapped order; any real depth beats it.
#define Z_EMPTY 0xFFFFFFFFu

// Order-preserving float -> uint mapping (monotone for all finite floats,
// including negatives), so atomicMin(uint) == float min.
__device__ __forceinline__ unsigned int fmap(float f) {
    unsigned int u = __float_as_uint(f);
    return (u & 0x80000000u) ? ~u : (u | 0x80000000u);
}
__device__ __forceinline__ float funmap(unsigned int u) {
    return (u & 0x80000000u) ? __uint_as_float(u ^ 0x80000000u)
                             : __uint_as_float(~u);
}

// True hardware XCD id (0..7 on MI355X). HW-verified readable on gfx950
// (learn_hip m09). All waves of a workgroup run on one CU -> one XCD, so
// this is workgroup-uniform.
__device__ __forceinline__ int xcc_id() {
    unsigned int x;
    asm volatile("s_getreg_b32 %0, hwreg(HW_REG_XCC_ID)" : "=s"(x));
    return (int)(x & (NXCD - 1));
}

__device__ __forceinline__ int ncopies_for(unsigned long long ws_size, int HW) {
    return (ws_size >= (unsigned long long)NXCD * HW * 4ull) ? NXCD : 1;
}

__global__ void init_zbuf(unsigned int* __restrict__ zbuf,
                          const int* __restrict__ pH, const int* __restrict__ pW,
                          unsigned long long ws_size) {
    int HW = pH[0] * pW[0];
    long long total = (long long)ncopies_for(ws_size, HW) * HW;
    for (long long i = blockIdx.x * (long long)blockDim.x + threadIdx.x; i < total;
         i += (long long)gridDim.x * blockDim.x)
        zbuf[i] = Z_EMPTY;
}

// One thread per (triangle, i); i = px sample index (blockIdx.y). Each thread
// walks the 12 py samples. 8-copy path: scatter-min into this XCD's private
// copy with a WORKGROUP-scope atomic -> executes at the local TCC on a cached
// line (no sc1 bypass), no memory-side traffic per op. Atomicity holds since
// copy c is only ever touched by XCD c. End-of-kernel release flushes L2.
__global__ void raster(const float* __restrict__ verts, const int* __restrict__ tris,
                       int T, const int* __restrict__ pH, const int* __restrict__ pW,
                       unsigned int* zbuf, unsigned long long ws_size) {
#pragma clang fp contract(off)
    int t = blockIdx.x * blockDim.x + threadIdx.x;
    if (t >= T) return;
    const int i = blockIdx.y;
    const int W = pW[0];
    const int H = pH[0];
    const int HW = W * H;
    const float Wm1 = (float)(W - 1);
    const float Hm1 = (float)(H - 1);

    const int nc = ncopies_for(ws_size, HW);           // uniform everywhere
    unsigned int* zslice = zbuf;
    if (nc == NXCD) zslice = zbuf + (size_t)xcc_id() * HW;

    int i0 = tris[t * 3 + 0], i1 = tris[t * 3 + 1], i2 = tris[t * 3 + 2];
    float x0 = verts[i0 * 3 + 0], y0 = verts[i0 * 3 + 1], z0 = verts[i0 * 3 + 2];
    float x1 = verts[i1 * 3 + 0], y1 = verts[i1 * 3 + 1], z1 = verts[i1 * 3 + 2];
    float x2 = verts[i2 * 3 + 0], y2 = verts[i2 * 3 + 1], z2 = verts[i2 * 3 + 2];

    // area exactly as reference
    float area = (x2 - x0) * (y1 - y0) - (y2 - y0) * (x1 - x0);
    if (!(fabsf(area) > 1e-8f)) return;  // all samples invalid -> BIG -> no-op

    float xmin = fminf(x0, fminf(x1, x2));
    float xmax = fmaxf(x0, fmaxf(x1, x2));
    float ymin = fminf(y0, fminf(y1, y2));
    float ymax = fmaxf(y0, fmaxf(y1, y2));

    // t_i = f32(i) * f32(1/11)  — matches jnp.linspace exactly (NOT i/11).
    float ti = (float)i * T_DELTA;
    float px = xmin + ti * (xmax - xmin);
    if (!(px >= 0.0f && px <= Wm1)) return;  // in_img fails for this whole column

    int ix = (int)fminf(fmaxf(rintf(px), 0.0f), Wm1);

    // Edge constants (hoisting products keeps identical f32 values).
    float e0dy = y2 - y1, e0dx = x2 - x1;  // edge(v1,v2)
    float e1dy = y0 - y2, e1dx = x0 - x2;  // edge(v2,v0)
    float e2dy = y1 - y0, e2dx = x1 - x0;  // edge(v0,v1)
    float a0 = (px - x1) * e0dy;
    float a1 = (px - x2) * e1dy;
    float a2 = (px - x0) * e2dy;

    float dy = ymax - ymin;
#pragma unroll
    for (int j = 0; j < KK; ++j) {
        float tj = (float)j * T_DELTA;  // compile-time, matches linspace
        float py = ymin + tj * dy;
        if (!(py >= 0.0f && py <= Hm1)) continue;
        float w0 = a0 - (py - y1) * e0dx;
        float w1 = a1 - (py - y2) * e1dx;
        float w2 = a2 - (py - y0) * e2dx;
        bool inside = (w0 >= 0.0f && w1 >= 0.0f && w2 >= 0.0f) ||
                      (w0 <= 0.0f && w1 <= 0.0f && w2 <= 0.0f);
        if (!inside) continue;
        float depth = ((w0 * z0 + w1 * z1) + w2 * z2) / area;  // left-assoc as XLA
        int iy = (int)fminf(fmaxf(rintf(py), 0.0f), Hm1);
        int idx = iy * W + ix;
        unsigned int d = fmap(depth);
        if (nc == NXCD) {
            __hip_atomic_fetch_min(&zslice[idx], d, __ATOMIC_RELAXED,
                                   __HIP_MEMORY_SCOPE_WORKGROUP);
        } else {
            atomicMin(&zslice[idx], d);  // device-scope fallback (round-9 path)
        }
    }
}

__global__ void visible_k(const float* __restrict__ verts, int N,
                          const int* __restrict__ pH, const int* __restrict__ pW,
                          const unsigned int* __restrict__ zbuf,
                          float* __restrict__ out, unsigned long long ws_size) {
#pragma clang fp contract(off)
    int n = blockIdx.x * blockDim.x + threadIdx.x;
    if (n >= N) return;
    const int W = pW[0];
    const int H = pH[0];
    const int HW = W * H;
    const int nc = ncopies_for(ws_size, HW);
    const float Wm1 = (float)(W - 1);
    const float Hm1 = (float)(H - 1);
    float x = verts[n * 3 + 0], y = verts[n * 3 + 1], z = verts[n * 3 + 2];
    bool in_img = (x >= 0.0f) && (x <= Wm1) && (y >= 0.0f) && (y <= Hm1);
    float r = 0.0f;
    if (in_img) {
        int ix = (int)fminf(fmaxf(rintf(x), 0.0f), Wm1);
        int iy = (int)fminf(fmaxf(rintf(y), 0.0f), Hm1);
        int idx = iy * W + ix;
        unsigned int m = Z_EMPTY;
        for (int c = 0; c < nc; ++c) {
            unsigned int u = zbuf[(size_t)c * HW + idx];
            m = (u < m) ? u : m;
        }
        float zb = (m == Z_EMPTY) ? BIG : funmap(m);
        r = (z <= zb + EPS_Z) ? 1.0f : 0.0f;
    }
    out[n] = r;
}

extern "C" void kernel_launch(void* const* d_in, const int* in_sizes, int n_in,
                              void* d_out, int out_size, void* d_ws, size_t ws_size,
                              hipStream_t stream) {
    const float* verts = (const float*)d_in[0];
    const int* tris = (const int*)d_in[1];
    const int* pH = (const int*)d_in[2];
    const int* pW = (const int*)d_in[3];
    int N = in_sizes[0] / 3;
    int T = in_sizes[1] / 3;
    unsigned int* zbuf = (unsigned int*)d_ws;  // up to 8 copies of H*W uints
    unsigned long long wsz = (unsigned long long)ws_size;

    init_zbuf<<<2048, 256, 0, stream>>>(zbuf, pH, pW, wsz);
    dim3 rgrid((T + 255) / 256, KK);
    raster<<<rgrid, 256, 0, stream>>>(verts, tris, T, pH, pW, zbuf, wsz);
    visible_k<<<(N + 255) / 256, 256, 0, stream>>>(verts, N, pH, pW, zbuf,
                                                   (float*)d_out, wsz);
}

// Round 13
// 112.288 us; speedup vs baseline: 2.2059x; 2.0927x over previous
//
#include <hip/hip_runtime.h>

// Exact-arithmetic replication of the JAX reference: no FMA contraction.
#pragma clang fp contract(off)

#define KK 12
#define EPS_Z 0.001f
#define BIG 1.0e10f

// JAX linspace(0,1,12): delta = f32(1/11) (one rounded division), t_k = k*delta.
#define T_DELTA (1.0f / 11.0f)

// "Empty" sentinel: max uint in mapped order; any real depth beats it.
#define Z_EMPTY 0xFFFFFFFFu

// Order-preserving float -> uint mapping (monotone for all finite floats,
// including negatives), so atomicMin(uint) == float min.
__device__ __forceinline__ unsigned int fmap(float f) {
    unsigned int u = __float_as_uint(f);
    return (u & 0x80000000u) ? ~u : (u | 0x80000000u);
}
__device__ __forceinline__ float funmap(unsigned int u) {
    return (u & 0x80000000u) ? __uint_as_float(u ^ 0x80000000u)
                             : __uint_as_float(~u);
}

// Workspace layout: ws[0 .. HW) = zbuf, ws[HW .. HW + HW/32) = live-pixel mask.
// use_mask is a pure function of (ws_size, HW) -> identical in all kernels.
__device__ __forceinline__ bool use_mask_for(unsigned long long ws_size, int HW) {
    return ws_size >= (unsigned long long)HW * 4ull + (unsigned long long)(HW / 8);
}

__global__ void init_ws(unsigned int* __restrict__ ws,
                        const int* __restrict__ pH, const int* __restrict__ pW,
                        unsigned long long ws_size) {
    int HW = pH[0] * pW[0];
    bool um = use_mask_for(ws_size, HW);
    long long total = HW + (um ? HW / 32 : 0);  // zbuf words + mask words
    for (long long i = blockIdx.x * (long long)blockDim.x + threadIdx.x; i < total;
         i += (long long)gridDim.x * blockDim.x)
        ws[i] = (i < HW) ? Z_EMPTY : 0u;
}

// Mark pixels that visible_k will read: one bit per pixel holding a vertex.
// Uses the IDENTICAL ix/iy computation as visible_k.
__global__ void mark_live(const float* __restrict__ verts, int N,
                          const int* __restrict__ pH, const int* __restrict__ pW,
                          unsigned int* __restrict__ ws,
                          unsigned long long ws_size) {
#pragma clang fp contract(off)
    const int W = pW[0];
    const int HW = W * pH[0];
    if (!use_mask_for(ws_size, HW)) return;
    unsigned int* mask = ws + HW;
    int n = blockIdx.x * blockDim.x + threadIdx.x;
    if (n >= N) return;
    const float Wm1 = (float)(W - 1);
    const float Hm1 = (float)(pH[0] - 1);
    float x = verts[n * 3 + 0], y = verts[n * 3 + 1];
    if ((x >= 0.0f) && (x <= Wm1) && (y >= 0.0f) && (y <= Hm1)) {
        int ix = (int)fminf(fmaxf(rintf(x), 0.0f), Wm1);
        int iy = (int)fminf(fmaxf(rintf(y), 0.0f), Hm1);
        int idx = iy * W + ix;
        atomicOr(&mask[idx >> 5], 1u << (idx & 31));
    }
}

// One thread per (triangle, i); i = px sample index (blockIdx.y). Each thread
// walks the 12 py samples. Samples on pixels no vertex occupies are skipped:
// visible_k never reads those zbuf entries, so their min is dead output.
// The mask is read-only during this dispatch -> normal cached loads.
__global__ void raster(const float* __restrict__ verts, const int* __restrict__ tris,
                       int T, const int* __restrict__ pH, const int* __restrict__ pW,
                       unsigned int* ws, unsigned long long ws_size) {
#pragma clang fp contract(off)
    int t = blockIdx.x * blockDim.x + threadIdx.x;
    if (t >= T) return;
    const int i = blockIdx.y;
    const int W = pW[0];
    const int H = pH[0];
    const int HW = W * H;
    const bool um = use_mask_for(ws_size, HW);
    unsigned int* zbuf = ws;
    const unsigned int* mask = ws + HW;
    const float Wm1 = (float)(W - 1);
    const float Hm1 = (float)(H - 1);

    int i0 = tris[t * 3 + 0], i1 = tris[t * 3 + 1], i2 = tris[t * 3 + 2];
    float x0 = verts[i0 * 3 + 0], y0 = verts[i0 * 3 + 1], z0 = verts[i0 * 3 + 2];
    float x1 = verts[i1 * 3 + 0], y1 = verts[i1 * 3 + 1], z1 = verts[i1 * 3 + 2];
    float x2 = verts[i2 * 3 + 0], y2 = verts[i2 * 3 + 1], z2 = verts[i2 * 3 + 2];

    // area exactly as reference
    float area = (x2 - x0) * (y1 - y0) - (y2 - y0) * (x1 - x0);
    if (!(fabsf(area) > 1e-8f)) return;  // all samples invalid -> BIG -> no-op

    float xmin = fminf(x0, fminf(x1, x2));
    float xmax = fmaxf(x0, fmaxf(x1, x2));
    float ymin = fminf(y0, fminf(y1, y2));
    float ymax = fmaxf(y0, fmaxf(y1, y2));

    // t_i = f32(i) * f32(1/11)  — matches jnp.linspace exactly (NOT i/11).
    float ti = (float)i * T_DELTA;
    float px = xmin + ti * (xmax - xmin);
    if (!(px >= 0.0f && px <= Wm1)) return;  // in_img fails for this whole column

    int ix = (int)fminf(fmaxf(rintf(px), 0.0f), Wm1);

    // Edge constants (hoisting products keeps identical f32 values).
    float e0dy = y2 - y1, e0dx = x2 - x1;  // edge(v1,v2)
    float e1dy = y0 - y2, e1dx = x0 - x2;  // edge(v2,v0)
    float e2dy = y1 - y0, e2dx = x1 - x0;  // edge(v0,v1)
    float a0 = (px - x1) * e0dy;
    float a1 = (px - x2) * e1dy;
    float a2 = (px - x0) * e2dy;

    float dy = ymax - ymin;
#pragma unroll
    for (int j = 0; j < KK; ++j) {
        float tj = (float)j * T_DELTA;  // compile-time, matches linspace
        float py = ymin + tj * dy;
        if (!(py >= 0.0f && py <= Hm1)) continue;
        float w0 = a0 - (py - y1) * e0dx;
        float w1 = a1 - (py - y2) * e1dx;
        float w2 = a2 - (py - y0) * e2dx;
        bool inside = (w0 >= 0.0f && w1 >= 0.0f && w2 >= 0.0f) ||
                      (w0 <= 0.0f && w1 <= 0.0f && w2 <= 0.0f);
        if (!inside) continue;
        float depth = ((w0 * z0 + w1 * z1) + w2 * z2) / area;  // left-assoc as XLA
        int iy = (int)fminf(fmaxf(rintf(py), 0.0f), Hm1);
        int idx = iy * W + ix;
        if (um) {
            unsigned int mw = mask[idx >> 5];          // cached read-only load
            if (!((mw >> (idx & 31)) & 1u)) continue;  // dead pixel: skip atomic
        }
        atomicMin(&zbuf[idx], fmap(depth));
    }
}

__global__ void visible_k(const float* __restrict__ verts, int N,
                          const int* __restrict__ pH, const int* __restrict__ pW,
                          const unsigned int* __restrict__ zbuf,
                          float* __restrict__ out) {
#pragma clang fp contract(off)
    int n = blockIdx.x * blockDim.x + threadIdx.x;
    if (n >= N) return;
    const int W = pW[0];
    const int H = pH[0];
    const float Wm1 = (float)(W - 1);
    const float Hm1 = (float)(H - 1);
    float x = verts[n * 3 + 0], y = verts[n * 3 + 1], z = verts[n * 3 + 2];
    bool in_img = (x >= 0.0f) && (x <= Wm1) && (y >= 0.0f) && (y <= Hm1);
    float r = 0.0f;
    if (in_img) {
        int ix = (int)fminf(fmaxf(rintf(x), 0.0f), Wm1);
        int iy = (int)fminf(fmaxf(rintf(y), 0.0f), Hm1);
        unsigned int u = zbuf[iy * W + ix];
        float zb = (u == Z_EMPTY) ? BIG : funmap(u);
        r = (z <= zb + EPS_Z) ? 1.0f : 0.0f;
    }
    out[n] = r;
}

extern "C" void kernel_launch(void* const* d_in, const int* in_sizes, int n_in,
                              void* d_out, int out_size, void* d_ws, size_t ws_size,
                              hipStream_t stream) {
    const float* verts = (const float*)d_in[0];
    const int* tris = (const int*)d_in[1];
    const int* pH = (const int*)d_in[2];
    const int* pW = (const int*)d_in[3];
    int N = in_sizes[0] / 3;
    int T = in_sizes[1] / 3;
    unsigned int* ws = (unsigned int*)d_ws;   // zbuf (HW) + mask (HW/32)
    unsigned long long wsz = (unsigned long long)ws_size;

    init_ws<<<1024, 256, 0, stream>>>(ws, pH, pW, wsz);
    mark_live<<<(N + 255) / 256, 256, 0, stream>>>(verts, N, pH, pW, ws, wsz);
    dim3 rgrid((T + 255) / 256, KK);
    raster<<<rgrid, 256, 0, stream>>>(verts, tris, T, pH, pW, ws, wsz);
    visible_k<<<(N + 255) / 256, 256, 0, stream>>>(verts, N, pH, pW, ws,
                                                   (float*)d_out);
}